// Round 5
// baseline (1021.713 us; speedup 1.0000x reference)
//
#include <hip/hip_runtime.h>
#include <cstddef>
#include <cstdint>

// ---------------------------------------------------------------------------
// attention_net_noc: pointer-network decode step.
// R8 = R7 (fixed reduce-scatter block_sum17, fast tanh, adjacent row pairs)
//    + R4's E-cache (float4 tile layout, proven)  -- R7 counters showed the
//      downstream sweeps are LATENCY-bound (HBM 7%, L3-resident), so the
//      emb recompute (3650 cy/wave vs 1300 cached) was pure critical-path
//      cost, not hidden by memory.
//    + R5's last-workgroup ticket tails (8 launches -> 5) -- exonerated: the
//      R5/R6 failures were entirely the sum17 layout bug (identical absmax
//      with AND without tickets), fixed in R7.
// ---------------------------------------------------------------------------

constexpr int NJ = 1000000;
constexpr int NM = 500000;
constexpr float NEGV = -1e8f;

constexpr int BLK = 256;
constexpr int ROWS_PER_BLK = 512;            // 2 adjacent rows per thread
constexpr int GB_J2 = (NJ + ROWS_PER_BLK - 1) / ROWS_PER_BLK;  // 1954
constexpr int GB_M2 = (NM + ROWS_PER_BLK - 1) / ROWS_PER_BLK;  // 977
constexpr int GB_TOT2 = GB_J2 + GB_M2;                          // 2931
constexpr int EBLK = ROWS_PER_BLK * 16;                         // 8192 floats/tile

// ---- workspace layout (float offsets from start of d_ws) ----
constexpr int S_QKJA = 0;    // 16: ja_Wq@g1 + ja_bq
constexpr int S_QK2J = 16;   // 16: aj_Wq@e_js + aj_bq
constexpr int S_QK2M = 32;   // 16: am_Wq@e_js + am_bq
constexpr int S_EJS  = 48;   // 16: E_j[sel_j]
constexpr int S_QKMA = 64;   // 16: ma_Wq@g2 + ma_bq
constexpr int S_LOGPJ = 80;
constexpr int S_SELJ  = 81;  // stored as float (exact, < 2^24)
constexpr int C_CTR   = 84;  // 4 int ticket counters (zeroed by k_zero)
constexpr int S_QK1J  = 96;  // 16: aj_Wq@last_j + aj_bq   (k_zero)
constexpr int S_QK1M  = 112; // 16: am_Wq@last_j + am_bq   (k_zero)
constexpr int P1J = 128;                       // GB_J2*17 glimpse partials (l, s[16])
constexpr int P1M = P1J + GB_J2 * 17;          // GB_M2*17
constexpr int P2V = P1M + GB_M2 * 17;          // GB_J2 argmax vals (sweepD reuses)
constexpr int P2I = P2V + GB_J2;
constexpr int P2L = P2I + GB_J2;
constexpr size_t E_OFF = 65536;                // float offset of E cache tiles
static_assert(P2L + GB_J2 <= (int)E_OFF, "partials overflow into E cache");

typedef float v2f __attribute__((ext_vector_type(2)));

struct Params {
    const float *jobs, *machines;
    const int *mask;
    const float *jW1, *jb1, *jW2, *jb2;
    const float *mW1, *mb1, *mW2, *mb2;
    const float *aj_Wq, *aj_bq, *aj_Wr, *aj_V;
    const float *am_Wq, *am_bq, *am_Wr, *am_V;
    const float *ja_Wq, *ja_bq, *ja_Wr, *ja_V;
    const float *ma_Wq, *ma_bq, *ma_Wr, *ma_V;
    const float *g1W, *g1b, *g2W, *g2b, *last_j;
    float *S;        // smalls + partials (in ws)
    float *Ej, *Em;  // embedding cache tiles (in ws; valid only if CACHE)
    float *out;
};

// ---------------------------------------------------------------------------
// device helpers
// ---------------------------------------------------------------------------

// tanh(x) = 1 - 2*rcp(exp2(x*2*log2e)+1). 5 instrs. abs err ~2e-7 vs np.tanh.
__device__ __forceinline__ float fast_tanh(float x) {
    float e = __builtin_amdgcn_exp2f(x * 2.8853900817779268f);  // 2/ln2
    float r = __builtin_amdgcn_rcpf(e + 1.0f);
    return fmaf(-2.0f, r, 1.0f);
}

__device__ __forceinline__ v2f vbc(float a) { v2f r; r.x = a; r.y = a; return r; }

// packed fma: one v_pk_fma_f32 issue slot for two fp32 FMAs (bit-identical)
__device__ __forceinline__ v2f vfma(float w, v2f b, v2f c) {
    return __builtin_elementwise_fma(vbc(w), b, c);
}
__device__ __forceinline__ v2f vfma2(v2f a, v2f b, v2f c) {
    return __builtin_elementwise_fma(a, b, c);
}
__device__ __forceinline__ v2f vtanh(v2f a) {
    v2f r; r.x = fast_tanh(a.x); r.y = fast_tanh(a.y); return r;
}

__device__ __forceinline__ void load16(const float* __restrict__ X, size_t r, float (&x)[16]) {
    const float4* p4 = reinterpret_cast<const float4*>(X) + r * 4;
    float4 a = p4[0], b = p4[1], c = p4[2], d = p4[3];
    x[0]=a.x; x[1]=a.y; x[2]=a.z; x[3]=a.w;
    x[4]=b.x; x[5]=b.y; x[6]=b.z; x[7]=b.w;
    x[8]=c.x; x[9]=c.y; x[10]=c.z; x[11]=c.w;
    x[12]=d.x; x[13]=d.y; x[14]=d.z; x[15]=d.w;
}

// load rows rA, rB and pack feature-wise into v2f lanes (.x=rowA, .y=rowB)
__device__ __forceinline__ void load16_v2(const float* __restrict__ X, size_t rA, size_t rB,
                                          v2f (&x)[16]) {
    float a[16], b[16];
    load16(X, rA, a);
    load16(X, rB, b);
#pragma unroll
    for (int k = 0; k < 16; ++k) { x[k].x = a[k]; x[k].y = b[k]; }
}

// E-cache tile: [8][256 threads * float4 {e[2k](rA,rB), e[2k+1](rA,rB)}]
// thread t owns rows (2t,2t+1): slot = kp*256 + t  (16B/lane, lane-contiguous)
__device__ __forceinline__ void ecache_store(float* __restrict__ Eb, int t, const v2f (&e)[16]) {
    float4* p4 = reinterpret_cast<float4*>(Eb);
#pragma unroll
    for (int kp = 0; kp < 8; ++kp)
        p4[kp * 256 + t] = make_float4(e[2*kp].x, e[2*kp].y, e[2*kp+1].x, e[2*kp+1].y);
}
__device__ __forceinline__ void ecache_load(const float* __restrict__ Eb, int t, v2f (&e)[16]) {
    const float4* p4 = reinterpret_cast<const float4*>(Eb);
#pragma unroll
    for (int kp = 0; kp < 8; ++kp) {
        float4 q = p4[kp * 256 + t];
        e[2*kp].x = q.x;   e[2*kp].y = q.y;
        e[2*kp+1].x = q.z; e[2*kp+1].y = q.w;
    }
}

// e = tanh(W2 @ tanh(W1 @ x + b1) + b2) for a packed row-pair
__device__ __forceinline__ void emb16_v2(const v2f (&x)[16],
                                         const float* __restrict__ W1, const float* __restrict__ b1,
                                         const float* __restrict__ W2, const float* __restrict__ b2,
                                         v2f (&e)[16]) {
    v2f h[16];
#pragma unroll
    for (int i = 0; i < 16; ++i) {
        v2f a = vbc(b1[i]);
#pragma unroll
        for (int k = 0; k < 16; ++k) a = vfma(W1[i * 16 + k], x[k], a);
        h[i] = vtanh(a);
    }
#pragma unroll
    for (int i = 0; i < 16; ++i) {
        v2f a = vbc(b2[i]);
#pragma unroll
        for (int k = 0; k < 16; ++k) a = vfma(W2[i * 16 + k], h[k], a);
        e[i] = vtanh(a);
    }
}

// logit = tanh(qk + Wr @ e) . V for a packed row-pair
__device__ __forceinline__ v2f att_logit_v2(const v2f (&e)[16], const float (&qk)[16],
                                            const float* __restrict__ Wr,
                                            const float* __restrict__ V) {
    v2f acc = vbc(0.0f);
#pragma unroll
    for (int i = 0; i < 16; ++i) {
        v2f r = vbc(qk[i]);
#pragma unroll
        for (int k = 0; k < 16; ++k) r = vfma(Wr[i * 16 + k], e[k], r);
        acc = vfma2(vbc(V[i]), vtanh(r), acc);
    }
    return acc;
}

__device__ __forceinline__ float wave_reduce_sum(float v) {
#pragma unroll
    for (int off = 32; off > 0; off >>= 1) v += __shfl_xor(v, off, 64);
    return v;
}

__device__ __forceinline__ void wave_reduce_argmax(float &v, int &idx) {
#pragma unroll
    for (int off = 32; off > 0; off >>= 1) {
        float ov = __shfl_xor(v, off, 64);
        int oi = __shfl_xor(idx, off, 64);
        if (ov > v || (ov == v && oi < idx)) { v = ov; idx = oi; }
    }
}

__device__ __forceinline__ float block_sum(float v) {
    __shared__ float sm[4];
    v = wave_reduce_sum(v);
    __syncthreads();
    if ((threadIdx.x & 63) == 0) sm[threadIdx.x >> 6] = v;
    __syncthreads();
    return sm[0] + sm[1] + sm[2] + sm[3];
}

__device__ __forceinline__ void block_argmax(float &v, int &i) {
    __shared__ float sv[4];
    __shared__ int si[4];
    wave_reduce_argmax(v, i);
    __syncthreads();
    if ((threadIdx.x & 63) == 0) { sv[threadIdx.x >> 6] = v; si[threadIdx.x >> 6] = i; }
    __syncthreads();
    float bv = sv[0]; int bi = si[0];
#pragma unroll
    for (int k = 1; k < 4; ++k)
        if (sv[k] > bv || (sv[k] == bv && si[k] < bi)) { bv = sv[k]; bi = si[k]; }
    v = bv; i = bi;
}

// Block-reduce (l, s[16]) -> dst[17] via reduce-scatter butterflies.
// OUTPUT LAYOUT (contract with all readers): dst[0] = l, dst[1+j] = s[j].
// 23 DS ops/wave vs 102 naive. Lane (0..15) ends owning s-index bitrev4(lane).
__device__ __forceinline__ void block_sum17(float l, const float (&s)[16], float* dst) {
    const int lane = threadIdx.x & 63;
    float c[8];
#pragma unroll
    for (int j = 0; j < 8; ++j) {          // xor 1: 16 -> 8
        const bool hi = lane & 1;
        float t = __shfl_xor(hi ? s[j] : s[j + 8], 1, 64);
        c[j] = (hi ? s[j + 8] : s[j]) + t;
    }
    float d[4];
#pragma unroll
    for (int j = 0; j < 4; ++j) {          // xor 2: 8 -> 4
        const bool hi = lane & 2;
        float t = __shfl_xor(hi ? c[j] : c[j + 4], 2, 64);
        d[j] = (hi ? c[j + 4] : c[j]) + t;
    }
    float e2[2];
#pragma unroll
    for (int j = 0; j < 2; ++j) {          // xor 4: 4 -> 2
        const bool hi = lane & 4;
        float t = __shfl_xor(hi ? d[j] : d[j + 2], 4, 64);
        e2[j] = (hi ? d[j + 2] : d[j]) + t;
    }
    float f;
    {                                       // xor 8: 2 -> 1
        const bool hi = lane & 8;
        float t = __shfl_xor(hi ? e2[0] : e2[1], 8, 64);
        f = (hi ? e2[1] : e2[0]) + t;
    }
    f += __shfl_xor(f, 16, 64);             // merge 16-lane groups
    f += __shfl_xor(f, 32, 64);
#pragma unroll
    for (int off = 32; off > 0; off >>= 1) l += __shfl_xor(l, off, 64);

    const int idx = ((lane & 1) << 3) | ((lane & 2) << 1) | ((lane & 4) >> 1) | ((lane & 8) >> 3);
    __shared__ float red[4][17];
    const int w = threadIdx.x >> 6;
    __syncthreads();                        // guard reuse across successive calls
    if (lane < 16) red[w][1 + idx] = f;     // s[idx] -> dst[1+idx]
    if (lane == 0) red[w][0] = l;           // l      -> dst[0]
    __syncthreads();
    if (threadIdx.x < 17)
        dst[threadIdx.x] = red[0][threadIdx.x] + red[1][threadIdx.x] + red[2][threadIdx.x] + red[3][threadIdx.x];
}

// Last-workgroup ticket (rocPRIM deviceReduce pattern). Producers: partial
// stores -> __syncthreads (drains each thread's vmcnt) -> __threadfence
// (device-scope release) -> atomic tick. Consumer (last block):
// __threadfence (acquire) -> read partials in fixed order (deterministic).
__device__ __forceinline__ bool last_block(int* ctr, int nblocks) {
    __shared__ int lastFlag;
    __syncthreads();
    __threadfence();
    if (threadIdx.x == 0) lastFlag = (atomicAdd(ctr, 1) == nblocks - 1);
    __syncthreads();
    if (!lastFlag) return false;
    __threadfence();
    return true;
}

// ---------------------------------------------------------------------------
// combine bodies (run by the last workgroup of the producing sweep)
// ---------------------------------------------------------------------------

// partials (P1J/P1M) -> g (g1 or g2) -> next-stage qk vector
__device__ __forceinline__ void combine_g_body(const Params& p, int phase) {
    const float* PJ = p.S + P1J;
    const float* PM = p.S + P1M;
    float lJ = 0.0f, lM = 0.0f, sJ[16], sM[16];
#pragma unroll
    for (int c = 0; c < 16; ++c) { sJ[c] = 0.0f; sM[c] = 0.0f; }
    for (int i = threadIdx.x; i < GB_J2; i += BLK) {
        lJ += PJ[i * 17];
#pragma unroll
        for (int c = 0; c < 16; ++c) sJ[c] += PJ[i * 17 + 1 + c];
    }
    for (int i = threadIdx.x; i < GB_M2; i += BLK) {
        lM += PM[i * 17];
#pragma unroll
        for (int c = 0; c < 16; ++c) sM[c] += PM[i * 17 + 1 + c];
    }
    __shared__ float totJ[17], totM[17];
    block_sum17(lJ, sJ, totJ);
    block_sum17(lM, sM, totM);
    __syncthreads();

    __shared__ float cb[48], gbuf[16];
    if (threadIdx.x < 16) {
        int i = threadIdx.x;
        cb[i]      = phase ? p.S[S_EJS + i] : p.last_j[i];
        cb[16 + i] = totJ[1 + i] / totJ[0];   // softmax-weighted sum / partition
        cb[32 + i] = totM[1 + i] / totM[0];
    }
    __syncthreads();
    const float* gW  = phase ? p.g2W : p.g1W;
    const float* gbv = phase ? p.g2b : p.g1b;
    if (threadIdx.x < 16) {
        int i = threadIdx.x;
        float a = gbv[i];
#pragma unroll
        for (int k = 0; k < 48; ++k) a = fmaf(gW[i * 48 + k], cb[k], a);
        gbuf[i] = fast_tanh(a);
    }
    __syncthreads();
    const float* Wq = phase ? p.ma_Wq : p.ja_Wq;
    const float* bq = phase ? p.ma_bq : p.ja_bq;
    const int off = phase ? S_QKMA : S_QKJA;
    if (threadIdx.x < 16) {
        int i = threadIdx.x;
        float a = bq[i];
#pragma unroll
        for (int k = 0; k < 16; ++k) a = fmaf(Wq[i * 16 + k], gbuf[k], a);
        p.S[off + i] = a;
    }
}

// global argmax over job logits; logp_j; e_js = emb(jobs[sel_j]); qk2j/qk2m
__device__ __forceinline__ void combine2_body(const Params& p) {
    float v = -3.4e38f; int vi = 0x7fffffff; float l = 0.0f;
    for (int i = threadIdx.x; i < GB_J2; i += BLK) {
        float pv = p.S[P2V + i];
        int pi = (int)p.S[P2I + i];
        if (pv > v || (pv == v && pi < vi)) { v = pv; vi = pi; }
        l += p.S[P2L + i];
    }
    l = block_sum(l);
    block_argmax(v, vi);
    const int sel = vi;

    __shared__ float xb[16], hb[16], eb[16];
    if (threadIdx.x < 16) xb[threadIdx.x] = p.jobs[(size_t)sel * 16 + threadIdx.x];
    __syncthreads();
    if (threadIdx.x < 16) {
        int i = threadIdx.x;
        float a = p.jb1[i];
#pragma unroll
        for (int k = 0; k < 16; ++k) a = fmaf(p.jW1[i * 16 + k], xb[k], a);
        hb[i] = fast_tanh(a);
    }
    __syncthreads();
    if (threadIdx.x < 16) {
        int i = threadIdx.x;
        float a = p.jb2[i];
#pragma unroll
        for (int k = 0; k < 16; ++k) a = fmaf(p.jW2[i * 16 + k], hb[k], a);
        float e = fast_tanh(a);
        eb[i] = e;
        p.S[S_EJS + i] = e;
    }
    __syncthreads();
    if (threadIdx.x < 16) {
        int i = threadIdx.x;
        float a1 = p.aj_bq[i], a2 = p.am_bq[i];
#pragma unroll
        for (int k = 0; k < 16; ++k) {
            a1 = fmaf(p.aj_Wq[i * 16 + k], eb[k], a1);
            a2 = fmaf(p.am_Wq[i * 16 + k], eb[k], a2);
        }
        p.S[S_QK2J + i] = a1;
        p.S[S_QK2M + i] = a2;
    }
    if (threadIdx.x == 0) {
        p.S[S_LOGPJ] = v - logf(l);     // log_softmax at the argmax
        p.S[S_SELJ] = (float)sel;
    }
}

// final combine -> outputs [sel_j, sel_m, logpas]
__device__ __forceinline__ void combine4_body(const Params& p) {
    float v = -3.4e38f; int vi = 0x7fffffff; float l = 0.0f;
    for (int i = threadIdx.x; i < GB_M2; i += BLK) {
        float pv = p.S[P2V + i];
        int pi = (int)p.S[P2I + i];
        if (pv > v || (pv == v && pi < vi)) { v = pv; vi = pi; }
        l += p.S[P2L + i];
    }
    l = block_sum(l);
    block_argmax(v, vi);
    if (threadIdx.x == 0) {
        p.out[0] = p.S[S_SELJ];
        p.out[1] = (float)vi;
        p.out[2] = p.S[S_LOGPJ] + (v - logf(l));
    }
}

// ---------------------------------------------------------------------------
// K0: zero ticket counters + precompute phase-1 query vectors qk1j/qk1m.
// ---------------------------------------------------------------------------
__global__ __launch_bounds__(64) void k_zero(Params p) {
    if (threadIdx.x < 32) {
        const bool isJ = threadIdx.x < 16;
        const int i = threadIdx.x & 15;
        const float* Wq = isJ ? p.aj_Wq : p.am_Wq;
        const float* bq = isJ ? p.aj_bq : p.am_bq;
        float a = bq[i];
#pragma unroll
        for (int k = 0; k < 16; ++k) a = fmaf(Wq[i * 16 + k], p.last_j[k], a);
        p.S[(isJ ? S_QK1J : S_QK1M) + i] = a;
    }
    if (threadIdx.x >= 60) reinterpret_cast<int*>(p.S + C_CTR)[threadIdx.x - 60] = 0;
}

// ---------------------------------------------------------------------------
// Sweep A: embeddings (cached if CACHE) + glimpse-1 partials; tail=combine_g(0)
// blocks [0,GB_J2) -> jobs, [GB_J2,GB_TOT2) -> machines. Rows (2t,2t+1).
// ---------------------------------------------------------------------------
template <bool CACHE>
__global__ __launch_bounds__(BLK) void k_sweepA(Params p) {
    const bool isJob = blockIdx.x < GB_J2;
    const float* X  = isJob ? p.jobs : p.machines;
    const float* W1 = isJob ? p.jW1 : p.mW1;
    const float* b1 = isJob ? p.jb1 : p.mb1;
    const float* W2 = isJob ? p.jW2 : p.mW2;
    const float* b2 = isJob ? p.jb2 : p.mb2;
    const float* Wr = isJob ? p.aj_Wr : p.am_Wr;
    const float* V  = isJob ? p.aj_V  : p.am_V;
    float* E = isJob ? p.Ej : p.Em;
    const int n  = isJob ? NJ : NM;
    const int b0 = isJob ? (int)blockIdx.x : (int)blockIdx.x - GB_J2;

    float qk[16];
    {
        const float* src = p.S + (isJob ? S_QK1J : S_QK1M);
#pragma unroll
        for (int i = 0; i < 16; ++i) qk[i] = src[i];
    }

    const int r0 = b0 * ROWS_PER_BLK + 2 * (int)threadIdx.x;
    const bool v = r0 < n;                 // n even => r0,r0+1 valid together
    const size_t a0 = (size_t)(v ? r0 : 0);
    const size_t a1 = a0 + (v ? 1 : 0);

    v2f x[16], e[16];
    load16_v2(X, a0, a1, x);
    emb16_v2(x, W1, b1, W2, b2, e);
    if (CACHE) ecache_store(E + (size_t)b0 * EBLK, (int)threadIdx.x, e);
    v2f lg = att_logit_v2(e, qk, Wr, V);
    // |logit| <= sum|V| ~ 0.6 -> exp never overflows; no max-shift needed.
    float pw0 = v ? __expf(lg.x) : 0.0f;
    float pw1 = v ? __expf(lg.y) : 0.0f;
    float l = pw0 + pw1, s[16];
#pragma unroll
    for (int i = 0; i < 16; ++i) s[i] = fmaf(pw0, e[i].x, pw1 * e[i].y);

    block_sum17(l, s, p.S + (isJob ? P1J : P1M) + (size_t)b0 * 17);

    if (last_block(reinterpret_cast<int*>(p.S + C_CTR) + 0, GB_TOT2))
        combine_g_body(p, 0);
}

// ---------------------------------------------------------------------------
// Sweep B: job pointer logits -> masked argmax + sum-exp partials; tail=combine2
// ---------------------------------------------------------------------------
template <bool CACHE>
__global__ __launch_bounds__(BLK) void k_sweepB(Params p) {
    float qk[16];
#pragma unroll
    for (int i = 0; i < 16; ++i) qk[i] = p.S[S_QKJA + i];

    const int r0 = blockIdx.x * ROWS_PER_BLK + 2 * (int)threadIdx.x;
    const bool v = r0 < NJ;
    const size_t a0 = (size_t)(v ? r0 : 0);
    const size_t a1 = a0 + (v ? 1 : 0);

    v2f e[16];
    if (CACHE) {
        ecache_load(p.Ej + (size_t)blockIdx.x * EBLK, (int)threadIdx.x, e);
    } else {
        v2f x[16];
        load16_v2(p.jobs, a0, a1, x);
        emb16_v2(x, p.jW1, p.jb1, p.jW2, p.jb2, e);
    }
    v2f lg = att_logit_v2(e, qk, p.ja_Wr, p.ja_V);

    int2 mq = make_int2(0, 0);
    if (v) mq = *reinterpret_cast<const int2*>(p.mask + r0);
    const bool m0 = v && (mq.x != 0);
    const bool m1 = v && (mq.y != 0);
    float l = (m0 ? __expf(lg.x) : 0.0f) + (m1 ? __expf(lg.y) : 0.0f);
    float am0 = m0 ? lg.x : NEGV - 1.0f;   // invalid rows below masked NEG
    float am1 = m1 ? lg.y : NEGV - 1.0f;
    float best;
    int bi;
    if (am0 >= am1) { best = am0; bi = r0; }
    else            { best = am1; bi = r0 + 1; }

    l = wave_reduce_sum(l);
    wave_reduce_argmax(best, bi);
    __shared__ float rl[4], rv[4];
    __shared__ int ri[4];
    int w = threadIdx.x >> 6, ln = threadIdx.x & 63;
    if (ln == 0) { rl[w] = l; rv[w] = best; ri[w] = bi; }
    __syncthreads();
    if (threadIdx.x == 0) {
        float L = rl[0] + rl[1] + rl[2] + rl[3];
        float vv = rv[0]; int i = ri[0];
#pragma unroll
        for (int k = 1; k < 4; ++k)
            if (rv[k] > vv || (rv[k] == vv && ri[k] < i)) { vv = rv[k]; i = ri[k]; }
        p.S[P2V + blockIdx.x] = vv;
        p.S[P2I + blockIdx.x] = (float)i;   // exact: i < 2^24
        p.S[P2L + blockIdx.x] = L;
    }

    if (last_block(reinterpret_cast<int*>(p.S + C_CTR) + 1, GB_J2))
        combine2_body(p);
}

// ---------------------------------------------------------------------------
// Sweep C: glimpse-2 over jobs (aj_*) and machines (am_*), query e_js;
// tail = combine_g(1). Partials into the (already consumed) P1 buffers.
// ---------------------------------------------------------------------------
template <bool CACHE>
__global__ __launch_bounds__(BLK) void k_sweepC(Params p) {
    const bool isJob = blockIdx.x < GB_J2;
    const float* Wr = isJob ? p.aj_Wr : p.am_Wr;
    const float* V  = isJob ? p.aj_V  : p.am_V;
    const float* E  = isJob ? p.Ej : p.Em;
    const float* X  = isJob ? p.jobs : p.machines;
    const float* W1 = isJob ? p.jW1 : p.mW1;
    const float* b1 = isJob ? p.jb1 : p.mb1;
    const float* W2 = isJob ? p.jW2 : p.mW2;
    const float* b2 = isJob ? p.jb2 : p.mb2;
    const int n  = isJob ? NJ : NM;
    const int b0 = isJob ? (int)blockIdx.x : (int)blockIdx.x - GB_J2;
    const int qoff = isJob ? S_QK2J : S_QK2M;

    float qk[16];
#pragma unroll
    for (int i = 0; i < 16; ++i) qk[i] = p.S[qoff + i];

    const int r0 = b0 * ROWS_PER_BLK + 2 * (int)threadIdx.x;
    const bool v = r0 < n;
    const size_t a0 = (size_t)(v ? r0 : 0);
    const size_t a1 = a0 + (v ? 1 : 0);

    v2f e[16];
    if (CACHE) {
        ecache_load(E + (size_t)b0 * EBLK, (int)threadIdx.x, e);
    } else {
        v2f x[16];
        load16_v2(X, a0, a1, x);
        emb16_v2(x, W1, b1, W2, b2, e);
    }
    v2f lg = att_logit_v2(e, qk, Wr, V);
    float pw0 = v ? __expf(lg.x) : 0.0f;
    float pw1 = v ? __expf(lg.y) : 0.0f;
    float l = pw0 + pw1, s[16];
#pragma unroll
    for (int i = 0; i < 16; ++i) s[i] = fmaf(pw0, e[i].x, pw1 * e[i].y);

    block_sum17(l, s, p.S + (isJob ? P1J : P1M) + (size_t)b0 * 17);

    if (last_block(reinterpret_cast<int*>(p.S + C_CTR) + 2, GB_TOT2))
        combine_g_body(p, 1);
}

// ---------------------------------------------------------------------------
// Sweep D: machine logits -> argmax + sum-exp partials; tail = combine4.
// ---------------------------------------------------------------------------
template <bool CACHE>
__global__ __launch_bounds__(BLK) void k_sweepD(Params p) {
    float qk[16];
#pragma unroll
    for (int i = 0; i < 16; ++i) qk[i] = p.S[S_QKMA + i];

    const int r0 = blockIdx.x * ROWS_PER_BLK + 2 * (int)threadIdx.x;
    const bool v = r0 < NM;
    const size_t a0 = (size_t)(v ? r0 : 0);
    const size_t a1 = a0 + (v ? 1 : 0);

    v2f e[16];
    if (CACHE) {
        ecache_load(p.Em + (size_t)blockIdx.x * EBLK, (int)threadIdx.x, e);
    } else {
        v2f x[16];
        load16_v2(p.machines, a0, a1, x);
        emb16_v2(x, p.mW1, p.mb1, p.mW2, p.mb2, e);
    }
    v2f lg = att_logit_v2(e, qk, p.ma_Wr, p.ma_V);
    float l = (v ? __expf(lg.x) : 0.0f) + (v ? __expf(lg.y) : 0.0f);
    float am0 = v ? lg.x : -3.4e38f;
    float am1 = v ? lg.y : -3.4e38f;
    float best;
    int bi;
    if (am0 >= am1) { best = am0; bi = r0; }
    else            { best = am1; bi = r0 + 1; }

    l = wave_reduce_sum(l);
    wave_reduce_argmax(best, bi);
    __shared__ float rl[4], rv[4];
    __shared__ int ri[4];
    int w = threadIdx.x >> 6, ln = threadIdx.x & 63;
    if (ln == 0) { rl[w] = l; rv[w] = best; ri[w] = bi; }
    __syncthreads();
    if (threadIdx.x == 0) {
        float L = rl[0] + rl[1] + rl[2] + rl[3];
        float vv = rv[0]; int i = ri[0];
#pragma unroll
        for (int k = 1; k < 4; ++k)
            if (rv[k] > vv || (rv[k] == vv && ri[k] < i)) { vv = rv[k]; i = ri[k]; }
        p.S[P2V + blockIdx.x] = vv;
        p.S[P2I + blockIdx.x] = (float)i;
        p.S[P2L + blockIdx.x] = L;
    }

    if (last_block(reinterpret_cast<int*>(p.S + C_CTR) + 3, GB_M2))
        combine4_body(p);
}

// ---------------------------------------------------------------------------
extern "C" void kernel_launch(void* const* d_in, const int* in_sizes, int n_in,
                              void* d_out, int out_size, void* d_ws, size_t ws_size,
                              hipStream_t stream) {
    Params p;
    p.jobs     = (const float*)d_in[0];
    p.machines = (const float*)d_in[1];
    p.mask     = (const int*)d_in[2];
    p.jW1 = (const float*)d_in[3];  p.jb1 = (const float*)d_in[4];
    p.jW2 = (const float*)d_in[5];  p.jb2 = (const float*)d_in[6];
    p.mW1 = (const float*)d_in[7];  p.mb1 = (const float*)d_in[8];
    p.mW2 = (const float*)d_in[9];  p.mb2 = (const float*)d_in[10];
    p.aj_Wq = (const float*)d_in[11]; p.aj_bq = (const float*)d_in[12];
    p.aj_Wr = (const float*)d_in[13]; p.aj_V  = (const float*)d_in[14];
    p.am_Wq = (const float*)d_in[15]; p.am_bq = (const float*)d_in[16];
    p.am_Wr = (const float*)d_in[17]; p.am_V  = (const float*)d_in[18];
    p.ja_Wq = (const float*)d_in[19]; p.ja_bq = (const float*)d_in[20];
    p.ja_Wr = (const float*)d_in[21]; p.ja_V  = (const float*)d_in[22];
    p.ma_Wq = (const float*)d_in[23]; p.ma_bq = (const float*)d_in[24];
    p.ma_Wr = (const float*)d_in[25]; p.ma_V  = (const float*)d_in[26];
    p.g1W = (const float*)d_in[27]; p.g1b = (const float*)d_in[28];
    p.g2W = (const float*)d_in[29]; p.g2b = (const float*)d_in[30];
    p.last_j = (const float*)d_in[31];
    p.S = (float*)d_ws;
    p.Ej = (float*)d_ws + E_OFF;
    p.Em = p.Ej + (size_t)GB_J2 * EBLK;
    p.out = (float*)d_out;

    const size_t needed = (E_OFF + (size_t)GB_TOT2 * EBLK) * sizeof(float);
    const bool cache = ws_size >= needed;

    k_zero<<<1, 64, 0, stream>>>(p);
    if (cache) {
        k_sweepA<true><<<GB_TOT2, BLK, 0, stream>>>(p);
        k_sweepB<true><<<GB_J2, BLK, 0, stream>>>(p);
        k_sweepC<true><<<GB_TOT2, BLK, 0, stream>>>(p);
        k_sweepD<true><<<GB_M2, BLK, 0, stream>>>(p);
    } else {
        k_sweepA<false><<<GB_TOT2, BLK, 0, stream>>>(p);
        k_sweepB<false><<<GB_J2, BLK, 0, stream>>>(p);
        k_sweepC<false><<<GB_TOT2, BLK, 0, stream>>>(p);
        k_sweepD<false><<<GB_M2, BLK, 0, stream>>>(p);
    }
}

// Round 6
// 292.578 us; speedup vs baseline: 3.4921x; 3.4921x over previous
//
#include <hip/hip_runtime.h>
#include <cstddef>
#include <cstdint>

// ---------------------------------------------------------------------------
// attention_net_noc: pointer-network decode step.
// R9 = the benched-304.7 R1 code (E-cache feature-interleaved float4 tiles,
//      separate 1-block combines, qk1 prologue in k_emb_g1, fast tanh,
//      adjacent row pairs) + two verified local deltas:
//  (1) block_sum17 as reduce-scatter butterflies (23 DS ops vs 102),
//      layout-fixed in R7 and verified there (absmax 0 across all 4 sites).
//  (2) int2 mask load in k_jlogits.
// R8 lesson (recorded): per-block device-scope __threadfence release while
// the kernel streams ~94 MB of dirty L2 (E-cache stores) causes cascading
// L2 writebacks -> 6x slowdown. Fused cross-block tails are off the table
// for store-heavy sweeps on gfx950.
// ---------------------------------------------------------------------------

constexpr int NJ = 1000000;
constexpr int NM = 500000;
constexpr float NEGV = -1e8f;

constexpr int BLK = 256;
constexpr int ROWS_PER_BLK = 512;            // 2 adjacent rows per thread
constexpr int GB_J2 = (NJ + ROWS_PER_BLK - 1) / ROWS_PER_BLK;  // 1954
constexpr int GB_M2 = (NM + ROWS_PER_BLK - 1) / ROWS_PER_BLK;  // 977
constexpr int GB_TOT2 = GB_J2 + GB_M2;                          // 2931
constexpr int EBLK = ROWS_PER_BLK * 16;                         // 8192 floats/tile

// ---- workspace layout (float offsets from start of d_ws) ----
constexpr int S_QKJA = 0;    // 16: ja_Wq@g1 + ja_bq
constexpr int S_QK2J = 16;   // 16: aj_Wq@e_js + aj_bq
constexpr int S_QK2M = 32;   // 16: am_Wq@e_js + am_bq
constexpr int S_EJS  = 48;   // 16: E_j[sel_j]
constexpr int S_QKMA = 64;   // 16: ma_Wq@g2 + ma_bq
constexpr int S_LOGPJ = 80;
constexpr int S_SELJ  = 81;  // stored as float (exact, < 2^24)
constexpr int P1J = 128;                       // GB_J2*17 glimpse partials (l, s[16])
constexpr int P1M = P1J + GB_J2 * 17;          // GB_M2*17
constexpr int P2V = P1M + GB_M2 * 17;          // GB_J2 argmax vals (mlogits reuses)
constexpr int P2I = P2V + GB_J2;
constexpr int P2L = P2I + GB_J2;
constexpr size_t E_OFF = 65536;                // float offset of E_j cache
static_assert(P2L + GB_J2 <= (int)E_OFF, "partials overflow into E cache");

typedef float v2f __attribute__((ext_vector_type(2)));

struct Params {
    const float *jobs, *machines;
    const int *mask;
    const float *jW1, *jb1, *jW2, *jb2;
    const float *mW1, *mb1, *mW2, *mb2;
    const float *aj_Wq, *aj_bq, *aj_Wr, *aj_V;
    const float *am_Wq, *am_bq, *am_Wr, *am_V;
    const float *ja_Wq, *ja_bq, *ja_Wr, *ja_V;
    const float *ma_Wq, *ma_bq, *ma_Wr, *ma_V;
    const float *g1W, *g1b, *g2W, *g2b, *last_j;
    float *S;        // smalls + partials (in ws)
    float *Ej, *Em;  // embedding cache tiles (in ws; valid only if CACHE)
    float *out;
};

// ---------------------------------------------------------------------------
// device helpers
// ---------------------------------------------------------------------------

// tanh(x) = 1 - 2*rcp(exp2(x*2*log2e)+1). 5 instrs. abs err ~2e-7 vs np.tanh.
__device__ __forceinline__ float fast_tanh(float x) {
    float e = __builtin_amdgcn_exp2f(x * 2.8853900817779268f);  // 2/ln2
    float r = __builtin_amdgcn_rcpf(e + 1.0f);
    return fmaf(-2.0f, r, 1.0f);
}

__device__ __forceinline__ v2f vbc(float a) { v2f r; r.x = a; r.y = a; return r; }

// packed fma: one v_pk_fma_f32 issue slot for two fp32 FMAs (bit-identical)
__device__ __forceinline__ v2f vfma(float w, v2f b, v2f c) {
    return __builtin_elementwise_fma(vbc(w), b, c);
}
__device__ __forceinline__ v2f vfma2(v2f a, v2f b, v2f c) {
    return __builtin_elementwise_fma(a, b, c);
}
__device__ __forceinline__ v2f vtanh(v2f a) {
    v2f r; r.x = fast_tanh(a.x); r.y = fast_tanh(a.y); return r;
}

__device__ __forceinline__ void load16(const float* __restrict__ X, size_t r, float (&x)[16]) {
    const float4* p4 = reinterpret_cast<const float4*>(X) + r * 4;
    float4 a = p4[0], b = p4[1], c = p4[2], d = p4[3];
    x[0]=a.x; x[1]=a.y; x[2]=a.z; x[3]=a.w;
    x[4]=b.x; x[5]=b.y; x[6]=b.z; x[7]=b.w;
    x[8]=c.x; x[9]=c.y; x[10]=c.z; x[11]=c.w;
    x[12]=d.x; x[13]=d.y; x[14]=d.z; x[15]=d.w;
}

// load rows rA, rB and pack feature-wise into v2f lanes (.x=rowA, .y=rowB)
__device__ __forceinline__ void load16_v2(const float* __restrict__ X, size_t rA, size_t rB,
                                          v2f (&x)[16]) {
    float a[16], b[16];
    load16(X, rA, a);
    load16(X, rB, b);
#pragma unroll
    for (int k = 0; k < 16; ++k) { x[k].x = a[k]; x[k].y = b[k]; }
}

// E-cache tile: [8][256 threads * float4 {e[2k](rA,rB), e[2k+1](rA,rB)}]
// thread t owns rows (2t,2t+1): slot = kp*256 + t  (16B/lane, lane-contiguous)
__device__ __forceinline__ void ecache_store(float* __restrict__ Eb, int t, const v2f (&e)[16]) {
    float4* p4 = reinterpret_cast<float4*>(Eb);
#pragma unroll
    for (int kp = 0; kp < 8; ++kp)
        p4[kp * 256 + t] = make_float4(e[2*kp].x, e[2*kp].y, e[2*kp+1].x, e[2*kp+1].y);
}
__device__ __forceinline__ void ecache_load(const float* __restrict__ Eb, int t, v2f (&e)[16]) {
    const float4* p4 = reinterpret_cast<const float4*>(Eb);
#pragma unroll
    for (int kp = 0; kp < 8; ++kp) {
        float4 q = p4[kp * 256 + t];
        e[2*kp].x = q.x;   e[2*kp].y = q.y;
        e[2*kp+1].x = q.z; e[2*kp+1].y = q.w;
    }
}

// e = tanh(W2 @ tanh(W1 @ x + b1) + b2) for a packed row-pair
__device__ __forceinline__ void emb16_v2(const v2f (&x)[16],
                                         const float* __restrict__ W1, const float* __restrict__ b1,
                                         const float* __restrict__ W2, const float* __restrict__ b2,
                                         v2f (&e)[16]) {
    v2f h[16];
#pragma unroll
    for (int i = 0; i < 16; ++i) {
        v2f a = vbc(b1[i]);
#pragma unroll
        for (int k = 0; k < 16; ++k) a = vfma(W1[i * 16 + k], x[k], a);
        h[i] = vtanh(a);
    }
#pragma unroll
    for (int i = 0; i < 16; ++i) {
        v2f a = vbc(b2[i]);
#pragma unroll
        for (int k = 0; k < 16; ++k) a = vfma(W2[i * 16 + k], h[k], a);
        e[i] = vtanh(a);
    }
}

// logit = tanh(qk + Wr @ e) . V for a packed row-pair
__device__ __forceinline__ v2f att_logit_v2(const v2f (&e)[16], const float (&qk)[16],
                                            const float* __restrict__ Wr,
                                            const float* __restrict__ V) {
    v2f acc = vbc(0.0f);
#pragma unroll
    for (int i = 0; i < 16; ++i) {
        v2f r = vbc(qk[i]);
#pragma unroll
        for (int k = 0; k < 16; ++k) r = vfma(Wr[i * 16 + k], e[k], r);
        acc = vfma2(vbc(V[i]), vtanh(r), acc);
    }
    return acc;
}

__device__ __forceinline__ float wave_reduce_sum(float v) {
#pragma unroll
    for (int off = 32; off > 0; off >>= 1) v += __shfl_xor(v, off, 64);
    return v;
}

__device__ __forceinline__ void wave_reduce_argmax(float &v, int &idx) {
#pragma unroll
    for (int off = 32; off > 0; off >>= 1) {
        float ov = __shfl_xor(v, off, 64);
        int oi = __shfl_xor(idx, off, 64);
        if (ov > v || (ov == v && oi < idx)) { v = ov; idx = oi; }
    }
}

__device__ __forceinline__ float block_sum(float v) {
    __shared__ float sm[4];
    v = wave_reduce_sum(v);
    __syncthreads();
    if ((threadIdx.x & 63) == 0) sm[threadIdx.x >> 6] = v;
    __syncthreads();
    return sm[0] + sm[1] + sm[2] + sm[3];
}

__device__ __forceinline__ void block_argmax(float &v, int &i) {
    __shared__ float sv[4];
    __shared__ int si[4];
    wave_reduce_argmax(v, i);
    __syncthreads();
    if ((threadIdx.x & 63) == 0) { sv[threadIdx.x >> 6] = v; si[threadIdx.x >> 6] = i; }
    __syncthreads();
    float bv = sv[0]; int bi = si[0];
#pragma unroll
    for (int k = 1; k < 4; ++k)
        if (sv[k] > bv || (sv[k] == bv && si[k] < bi)) { bv = sv[k]; bi = si[k]; }
    v = bv; i = bi;
}

// Block-reduce (l, s[16]) -> dst[17] via reduce-scatter butterflies.
// OUTPUT LAYOUT (contract with all readers): dst[0] = l, dst[1+j] = s[j].
// 23 DS ops/wave vs 102 naive. Verified in R7 (absmax 0 across all sites).
__device__ __forceinline__ void block_sum17(float l, const float (&s)[16], float* dst) {
    const int lane = threadIdx.x & 63;
    float c[8];
#pragma unroll
    for (int j = 0; j < 8; ++j) {          // xor 1: 16 -> 8
        const bool hi = lane & 1;
        float t = __shfl_xor(hi ? s[j] : s[j + 8], 1, 64);
        c[j] = (hi ? s[j + 8] : s[j]) + t;
    }
    float d[4];
#pragma unroll
    for (int j = 0; j < 4; ++j) {          // xor 2: 8 -> 4
        const bool hi = lane & 2;
        float t = __shfl_xor(hi ? c[j] : c[j + 4], 2, 64);
        d[j] = (hi ? c[j + 4] : c[j]) + t;
    }
    float e2[2];
#pragma unroll
    for (int j = 0; j < 2; ++j) {          // xor 4: 4 -> 2
        const bool hi = lane & 4;
        float t = __shfl_xor(hi ? d[j] : d[j + 2], 4, 64);
        e2[j] = (hi ? d[j + 2] : d[j]) + t;
    }
    float f;
    {                                       // xor 8: 2 -> 1
        const bool hi = lane & 8;
        float t = __shfl_xor(hi ? e2[0] : e2[1], 8, 64);
        f = (hi ? e2[1] : e2[0]) + t;
    }
    f += __shfl_xor(f, 16, 64);             // merge 16-lane groups
    f += __shfl_xor(f, 32, 64);
#pragma unroll
    for (int off = 32; off > 0; off >>= 1) l += __shfl_xor(l, off, 64);

    const int idx = ((lane & 1) << 3) | ((lane & 2) << 1) | ((lane & 4) >> 1) | ((lane & 8) >> 3);
    __shared__ float red[4][17];
    const int w = threadIdx.x >> 6;
    __syncthreads();                        // guard reuse across successive calls
    if (lane < 16) red[w][1 + idx] = f;     // s[idx] -> dst[1+idx]
    if (lane == 0) red[w][0] = l;           // l      -> dst[0]
    __syncthreads();
    if (threadIdx.x < 17)
        dst[threadIdx.x] = red[0][threadIdx.x] + red[1][threadIdx.x] + red[2][threadIdx.x] + red[3][threadIdx.x];
}

// ---------------------------------------------------------------------------
// K1: embeddings (cached to ws if CACHE) + glimpse-1 partial sums.
// blocks [0,GB_J2) -> jobs, [GB_J2,GB_TOT2) -> machines. Rows (2t,2t+1).
// qk1 (Wq@last_j+bq) computed per-block in a 16-thread prologue.
// ---------------------------------------------------------------------------
template <bool CACHE>
__global__ __launch_bounds__(BLK) void k_emb_g1(Params p) {
    const bool isJob = blockIdx.x < GB_J2;
    const float* X  = isJob ? p.jobs : p.machines;
    const float* W1 = isJob ? p.jW1 : p.mW1;
    const float* b1 = isJob ? p.jb1 : p.mb1;
    const float* W2 = isJob ? p.jW2 : p.mW2;
    const float* b2 = isJob ? p.jb2 : p.mb2;
    const float* Wr = isJob ? p.aj_Wr : p.am_Wr;
    const float* V  = isJob ? p.aj_V  : p.am_V;
    float* E = isJob ? p.Ej : p.Em;
    const int n  = isJob ? NJ : NM;
    const int b0 = isJob ? (int)blockIdx.x : (int)blockIdx.x - GB_J2;

    __shared__ float qks[16];
    if (threadIdx.x < 16) {
        const float* Wq = isJob ? p.aj_Wq : p.am_Wq;
        const float* bq = isJob ? p.aj_bq : p.am_bq;
        const int i = threadIdx.x;
        float a = bq[i];
#pragma unroll
        for (int k = 0; k < 16; ++k) a = fmaf(Wq[i * 16 + k], p.last_j[k], a);
        qks[i] = a;
    }
    __syncthreads();
    float qk[16];
#pragma unroll
    for (int i = 0; i < 16; ++i) qk[i] = qks[i];

    const int r0 = b0 * ROWS_PER_BLK + 2 * (int)threadIdx.x;
    const bool v = r0 < n;                 // n even => r0,r0+1 valid together
    const size_t a0 = (size_t)(v ? r0 : 0);
    const size_t a1 = a0 + (v ? 1 : 0);

    v2f x[16], e[16];
    load16_v2(X, a0, a1, x);
    emb16_v2(x, W1, b1, W2, b2, e);
    if (CACHE) ecache_store(E + (size_t)b0 * EBLK, (int)threadIdx.x, e);
    v2f lg = att_logit_v2(e, qk, Wr, V);
    // |logit| <= sum|V| ~ 0.6 -> exp never overflows; no max-shift needed.
    float pw0 = v ? __expf(lg.x) : 0.0f;
    float pw1 = v ? __expf(lg.y) : 0.0f;
    float l = pw0 + pw1, s[16];
#pragma unroll
    for (int i = 0; i < 16; ++i) s[i] = fmaf(pw0, e[i].x, pw1 * e[i].y);

    block_sum17(l, s, p.S + (isJob ? P1J : P1M) + (size_t)b0 * 17);
}

// ---------------------------------------------------------------------------
// Combine partials -> g (g1 or g2) -> next-stage qk vector. Single block.
// ---------------------------------------------------------------------------
__global__ __launch_bounds__(BLK) void k_combine_g(Params p, int phase) {
    const float* PJ = p.S + P1J;
    const float* PM = p.S + P1M;
    float lJ = 0.0f, lM = 0.0f, sJ[16], sM[16];
#pragma unroll
    for (int c = 0; c < 16; ++c) { sJ[c] = 0.0f; sM[c] = 0.0f; }
    for (int i = threadIdx.x; i < GB_J2; i += BLK) {
        lJ += PJ[i * 17];
#pragma unroll
        for (int c = 0; c < 16; ++c) sJ[c] += PJ[i * 17 + 1 + c];
    }
    for (int i = threadIdx.x; i < GB_M2; i += BLK) {
        lM += PM[i * 17];
#pragma unroll
        for (int c = 0; c < 16; ++c) sM[c] += PM[i * 17 + 1 + c];
    }
    __shared__ float totJ[17], totM[17];
    block_sum17(lJ, sJ, totJ);
    block_sum17(lM, sM, totM);
    __syncthreads();

    __shared__ float cb[48], gbuf[16];
    if (threadIdx.x < 16) {
        int i = threadIdx.x;
        cb[i]      = phase ? p.S[S_EJS + i] : p.last_j[i];
        cb[16 + i] = totJ[1 + i] / totJ[0];   // softmax-weighted sum / partition
        cb[32 + i] = totM[1 + i] / totM[0];
    }
    __syncthreads();
    const float* gW  = phase ? p.g2W : p.g1W;
    const float* gbv = phase ? p.g2b : p.g1b;
    if (threadIdx.x < 16) {
        int i = threadIdx.x;
        float a = gbv[i];
#pragma unroll
        for (int k = 0; k < 48; ++k) a = fmaf(gW[i * 48 + k], cb[k], a);
        gbuf[i] = fast_tanh(a);
    }
    __syncthreads();
    const float* Wq = phase ? p.ma_Wq : p.ja_Wq;
    const float* bq = phase ? p.ma_bq : p.ja_bq;
    const int off = phase ? S_QKMA : S_QKJA;
    if (threadIdx.x < 16) {
        int i = threadIdx.x;
        float a = bq[i];
#pragma unroll
        for (int k = 0; k < 16; ++k) a = fmaf(Wq[i * 16 + k], gbuf[k], a);
        p.S[off + i] = a;
    }
}

// ---------------------------------------------------------------------------
// K3: job pointer logits -> masked argmax + sum-exp partials. Rows (2t,2t+1).
// ---------------------------------------------------------------------------
template <bool CACHE>
__global__ __launch_bounds__(BLK) void k_jlogits(Params p) {
    float qk[16];
#pragma unroll
    for (int i = 0; i < 16; ++i) qk[i] = p.S[S_QKJA + i];

    const int r0 = blockIdx.x * ROWS_PER_BLK + 2 * (int)threadIdx.x;
    const bool v = r0 < NJ;
    const size_t a0 = (size_t)(v ? r0 : 0);
    const size_t a1 = a0 + (v ? 1 : 0);

    v2f e[16];
    if (CACHE) {
        ecache_load(p.Ej + (size_t)blockIdx.x * EBLK, (int)threadIdx.x, e);
    } else {
        v2f x[16];
        load16_v2(p.jobs, a0, a1, x);
        emb16_v2(x, p.jW1, p.jb1, p.jW2, p.jb2, e);
    }
    v2f lg = att_logit_v2(e, qk, p.ja_Wr, p.ja_V);

    int2 mq = make_int2(0, 0);
    if (v) mq = *reinterpret_cast<const int2*>(p.mask + r0);   // r0 even -> 8B aligned
    const bool m0 = v && (mq.x != 0);
    const bool m1 = v && (mq.y != 0);
    float l = (m0 ? __expf(lg.x) : 0.0f) + (m1 ? __expf(lg.y) : 0.0f);
    float am0 = m0 ? lg.x : NEGV - 1.0f;   // invalid rows below masked NEG
    float am1 = m1 ? lg.y : NEGV - 1.0f;
    float best;
    int bi;
    if (am0 >= am1) { best = am0; bi = r0; }
    else            { best = am1; bi = r0 + 1; }

    l = wave_reduce_sum(l);
    wave_reduce_argmax(best, bi);
    __shared__ float rl[4], rv[4];
    __shared__ int ri[4];
    int w = threadIdx.x >> 6, ln = threadIdx.x & 63;
    if (ln == 0) { rl[w] = l; rv[w] = best; ri[w] = bi; }
    __syncthreads();
    if (threadIdx.x == 0) {
        float L = rl[0] + rl[1] + rl[2] + rl[3];
        float vv = rv[0]; int i = ri[0];
#pragma unroll
        for (int k = 1; k < 4; ++k)
            if (rv[k] > vv || (rv[k] == vv && ri[k] < i)) { vv = rv[k]; i = ri[k]; }
        p.S[P2V + blockIdx.x] = vv;
        p.S[P2I + blockIdx.x] = (float)i;   // exact: i < 2^24
        p.S[P2L + blockIdx.x] = L;
    }
}

// ---------------------------------------------------------------------------
// C2: global argmax over job logits; logp_j; e_js = emb(jobs[sel_j]); qk2j/qk2m
// ---------------------------------------------------------------------------
__global__ __launch_bounds__(BLK) void k_combine2(Params p) {
    float v = -3.4e38f; int vi = 0x7fffffff; float l = 0.0f;
    for (int i = threadIdx.x; i < GB_J2; i += BLK) {
        float pv = p.S[P2V + i];
        int pi = (int)p.S[P2I + i];
        if (pv > v || (pv == v && pi < vi)) { v = pv; vi = pi; }
        l += p.S[P2L + i];
    }
    l = block_sum(l);
    block_argmax(v, vi);
    const int sel = vi;

    __shared__ float xb[16], hb[16], eb[16];
    if (threadIdx.x < 16) xb[threadIdx.x] = p.jobs[(size_t)sel * 16 + threadIdx.x];
    __syncthreads();
    if (threadIdx.x < 16) {
        int i = threadIdx.x;
        float a = p.jb1[i];
#pragma unroll
        for (int k = 0; k < 16; ++k) a = fmaf(p.jW1[i * 16 + k], xb[k], a);
        hb[i] = fast_tanh(a);
    }
    __syncthreads();
    if (threadIdx.x < 16) {
        int i = threadIdx.x;
        float a = p.jb2[i];
#pragma unroll
        for (int k = 0; k < 16; ++k) a = fmaf(p.jW2[i * 16 + k], hb[k], a);
        float e = fast_tanh(a);
        eb[i] = e;
        p.S[S_EJS + i] = e;
    }
    __syncthreads();
    if (threadIdx.x < 16) {
        int i = threadIdx.x;
        float a1 = p.aj_bq[i], a2 = p.am_bq[i];
#pragma unroll
        for (int k = 0; k < 16; ++k) {
            a1 = fmaf(p.aj_Wq[i * 16 + k], eb[k], a1);
            a2 = fmaf(p.am_Wq[i * 16 + k], eb[k], a2);
        }
        p.S[S_QK2J + i] = a1;
        p.S[S_QK2M + i] = a2;
    }
    if (threadIdx.x == 0) {
        p.S[S_LOGPJ] = v - logf(l);     // log_softmax at the argmax
        p.S[S_SELJ] = (float)sel;
    }
}

// ---------------------------------------------------------------------------
// K4: glimpse-2 over jobs (aj_*) and machines (am_*), query e_js. Rows (2t,2t+1).
// Writes partials into the (already consumed) P1 buffers.
// ---------------------------------------------------------------------------
template <bool CACHE>
__global__ __launch_bounds__(BLK) void k_glimpse2(Params p) {
    const bool isJob = blockIdx.x < GB_J2;
    const float* Wr = isJob ? p.aj_Wr : p.am_Wr;
    const float* V  = isJob ? p.aj_V  : p.am_V;
    const float* E  = isJob ? p.Ej : p.Em;
    const float* X  = isJob ? p.jobs : p.machines;
    const float* W1 = isJob ? p.jW1 : p.mW1;
    const float* b1 = isJob ? p.jb1 : p.mb1;
    const float* W2 = isJob ? p.jW2 : p.mW2;
    const float* b2 = isJob ? p.jb2 : p.mb2;
    const int n  = isJob ? NJ : NM;
    const int b0 = isJob ? (int)blockIdx.x : (int)blockIdx.x - GB_J2;
    const int qoff = isJob ? S_QK2J : S_QK2M;

    float qk[16];
#pragma unroll
    for (int i = 0; i < 16; ++i) qk[i] = p.S[qoff + i];

    const int r0 = b0 * ROWS_PER_BLK + 2 * (int)threadIdx.x;
    const bool v = r0 < n;
    const size_t a0 = (size_t)(v ? r0 : 0);
    const size_t a1 = a0 + (v ? 1 : 0);

    v2f e[16];
    if (CACHE) {
        ecache_load(E + (size_t)b0 * EBLK, (int)threadIdx.x, e);
    } else {
        v2f x[16];
        load16_v2(X, a0, a1, x);
        emb16_v2(x, W1, b1, W2, b2, e);
    }
    v2f lg = att_logit_v2(e, qk, Wr, V);
    float pw0 = v ? __expf(lg.x) : 0.0f;
    float pw1 = v ? __expf(lg.y) : 0.0f;
    float l = pw0 + pw1, s[16];
#pragma unroll
    for (int i = 0; i < 16; ++i) s[i] = fmaf(pw0, e[i].x, pw1 * e[i].y);

    block_sum17(l, s, p.S + (isJob ? P1J : P1M) + (size_t)b0 * 17);
}

// ---------------------------------------------------------------------------
// K5: machine logits -> argmax + sum-exp partials. Rows (2t,2t+1).
// Writes into the (already consumed) P2 buffers.
// ---------------------------------------------------------------------------
template <bool CACHE>
__global__ __launch_bounds__(BLK) void k_mlogits(Params p) {
    float qk[16];
#pragma unroll
    for (int i = 0; i < 16; ++i) qk[i] = p.S[S_QKMA + i];

    const int r0 = blockIdx.x * ROWS_PER_BLK + 2 * (int)threadIdx.x;
    const bool v = r0 < NM;
    const size_t a0 = (size_t)(v ? r0 : 0);
    const size_t a1 = a0 + (v ? 1 : 0);

    v2f e[16];
    if (CACHE) {
        ecache_load(p.Em + (size_t)blockIdx.x * EBLK, (int)threadIdx.x, e);
    } else {
        v2f x[16];
        load16_v2(p.machines, a0, a1, x);
        emb16_v2(x, p.mW1, p.mb1, p.mW2, p.mb2, e);
    }
    v2f lg = att_logit_v2(e, qk, p.ma_Wr, p.ma_V);
    float l = (v ? __expf(lg.x) : 0.0f) + (v ? __expf(lg.y) : 0.0f);
    float am0 = v ? lg.x : -3.4e38f;
    float am1 = v ? lg.y : -3.4e38f;
    float best;
    int bi;
    if (am0 >= am1) { best = am0; bi = r0; }
    else            { best = am1; bi = r0 + 1; }

    l = wave_reduce_sum(l);
    wave_reduce_argmax(best, bi);
    __shared__ float rl[4], rv[4];
    __shared__ int ri[4];
    int w = threadIdx.x >> 6, ln = threadIdx.x & 63;
    if (ln == 0) { rl[w] = l; rv[w] = best; ri[w] = bi; }
    __syncthreads();
    if (threadIdx.x == 0) {
        float L = rl[0] + rl[1] + rl[2] + rl[3];
        float vv = rv[0]; int i = ri[0];
#pragma unroll
        for (int k = 1; k < 4; ++k)
            if (rv[k] > vv || (rv[k] == vv && ri[k] < i)) { vv = rv[k]; i = ri[k]; }
        p.S[P2V + blockIdx.x] = vv;
        p.S[P2I + blockIdx.x] = (float)i;
        p.S[P2L + blockIdx.x] = L;
    }
}

// ---------------------------------------------------------------------------
// C4: final combine -> outputs [sel_j, sel_m, logpas] as float32
// ---------------------------------------------------------------------------
__global__ __launch_bounds__(BLK) void k_combine4(Params p) {
    float v = -3.4e38f; int vi = 0x7fffffff; float l = 0.0f;
    for (int i = threadIdx.x; i < GB_M2; i += BLK) {
        float pv = p.S[P2V + i];
        int pi = (int)p.S[P2I + i];
        if (pv > v || (pv == v && pi < vi)) { v = pv; vi = pi; }
        l += p.S[P2L + i];
    }
    l = block_sum(l);
    block_argmax(v, vi);
    if (threadIdx.x == 0) {
        p.out[0] = p.S[S_SELJ];
        p.out[1] = (float)vi;
        p.out[2] = p.S[S_LOGPJ] + (v - logf(l));
    }
}

// ---------------------------------------------------------------------------
extern "C" void kernel_launch(void* const* d_in, const int* in_sizes, int n_in,
                              void* d_out, int out_size, void* d_ws, size_t ws_size,
                              hipStream_t stream) {
    Params p;
    p.jobs     = (const float*)d_in[0];
    p.machines = (const float*)d_in[1];
    p.mask     = (const int*)d_in[2];
    p.jW1 = (const float*)d_in[3];  p.jb1 = (const float*)d_in[4];
    p.jW2 = (const float*)d_in[5];  p.jb2 = (const float*)d_in[6];
    p.mW1 = (const float*)d_in[7];  p.mb1 = (const float*)d_in[8];
    p.mW2 = (const float*)d_in[9];  p.mb2 = (const float*)d_in[10];
    p.aj_Wq = (const float*)d_in[11]; p.aj_bq = (const float*)d_in[12];
    p.aj_Wr = (const float*)d_in[13]; p.aj_V  = (const float*)d_in[14];
    p.am_Wq = (const float*)d_in[15]; p.am_bq = (const float*)d_in[16];
    p.am_Wr = (const float*)d_in[17]; p.am_V  = (const float*)d_in[18];
    p.ja_Wq = (const float*)d_in[19]; p.ja_bq = (const float*)d_in[20];
    p.ja_Wr = (const float*)d_in[21]; p.ja_V  = (const float*)d_in[22];
    p.ma_Wq = (const float*)d_in[23]; p.ma_bq = (const float*)d_in[24];
    p.ma_Wr = (const float*)d_in[25]; p.ma_V  = (const float*)d_in[26];
    p.g1W = (const float*)d_in[27]; p.g1b = (const float*)d_in[28];
    p.g2W = (const float*)d_in[29]; p.g2b = (const float*)d_in[30];
    p.last_j = (const float*)d_in[31];
    p.S = (float*)d_ws;
    p.Ej = (float*)d_ws + E_OFF;
    p.Em = p.Ej + (size_t)GB_J2 * EBLK;
    p.out = (float*)d_out;

    const size_t needed = (E_OFF + (size_t)GB_TOT2 * EBLK) * sizeof(float);
    const bool cache = ws_size >= needed;

    if (cache) {
        k_emb_g1<true><<<GB_TOT2, BLK, 0, stream>>>(p);
        k_combine_g<<<1, BLK, 0, stream>>>(p, 0);
        k_jlogits<true><<<GB_J2, BLK, 0, stream>>>(p);
        k_combine2<<<1, BLK, 0, stream>>>(p);
        k_glimpse2<true><<<GB_TOT2, BLK, 0, stream>>>(p);
        k_combine_g<<<1, BLK, 0, stream>>>(p, 1);
        k_mlogits<true><<<GB_M2, BLK, 0, stream>>>(p);
        k_combine4<<<1, BLK, 0, stream>>>(p);
    } else {
        k_emb_g1<false><<<GB_TOT2, BLK, 0, stream>>>(p);
        k_combine_g<<<1, BLK, 0, stream>>>(p, 0);
        k_jlogits<false><<<GB_J2, BLK, 0, stream>>>(p);
        k_combine2<<<1, BLK, 0, stream>>>(p);
        k_glimpse2<false><<<GB_TOT2, BLK, 0, stream>>>(p);
        k_combine_g<<<1, BLK, 0, stream>>>(p, 1);
        k_mlogits<false><<<GB_M2, BLK, 0, stream>>>(p);
        k_combine4<<<1, BLK, 0, stream>>>(p);
    }
}

// Round 7
// 286.861 us; speedup vs baseline: 3.5617x; 1.0199x over previous
//
#include <hip/hip_runtime.h>
#include <cstddef>
#include <cstdint>

// ---------------------------------------------------------------------------
// attention_net_noc: pointer-network decode step.
// R10 = R9 (292.6 us best: E-cache float4 tiles, reduce-scatter sum17,
//       separate combines, fast tanh) with 4 ROWS/THREAD (two v2f pipelines):
//  - 16 independent global loads in flight per wave (was 8) -> 2x memory-level
//    parallelism for the latency-bound sweeps (R9: VALUBusy 47%, HBM 26%,
//    occupancy 42% -- nothing saturated).
//  - per-row cost of qk prologue / block reduction / scheduling halves.
//  - grid: emb+glimpse2 2931->1466, jlogits 1954->977, mlogits 977->489.
//  - VGPR ~110 (cap 4 waves/SIMD = 50% occ, above measured 42%).
// Numerics per row unchanged; only per-thread partial grouping differs
// (same class of change as R1->R4->R7, all absmax 0).
// ---------------------------------------------------------------------------

constexpr int NJ = 1000000;
constexpr int NM = 500000;
constexpr float NEGV = -1e8f;

constexpr int BLK = 256;
constexpr int ROWS_PER_BLK = 1024;           // 4 adjacent rows per thread
constexpr int GB_J = (NJ + ROWS_PER_BLK - 1) / ROWS_PER_BLK;   // 977
constexpr int GB_M = (NM + ROWS_PER_BLK - 1) / ROWS_PER_BLK;   // 489
constexpr int GB_TOT = GB_J + GB_M;                             // 1466
constexpr int EBLK = ROWS_PER_BLK * 16;                         // 16384 floats/tile

// ---- workspace layout (float offsets from start of d_ws) ----
constexpr int S_QKJA = 0;    // 16: ja_Wq@g1 + ja_bq
constexpr int S_QK2J = 16;   // 16: aj_Wq@e_js + aj_bq
constexpr int S_QK2M = 32;   // 16: am_Wq@e_js + am_bq
constexpr int S_EJS  = 48;   // 16: E_j[sel_j]
constexpr int S_QKMA = 64;   // 16: ma_Wq@g2 + ma_bq
constexpr int S_LOGPJ = 80;
constexpr int S_SELJ  = 81;  // stored as float (exact, < 2^24)
constexpr int P1J = 128;                       // GB_J*17 glimpse partials (l, s[16])
constexpr int P1M = P1J + GB_J * 17;           // GB_M*17
constexpr int P2V = P1M + GB_M * 17;           // GB_J argmax vals (mlogits reuses)
constexpr int P2I = P2V + GB_J;
constexpr int P2L = P2I + GB_J;
constexpr size_t E_OFF = 65536;                // float offset of E cache tiles
static_assert(P2L + GB_J <= (int)E_OFF, "partials overflow into E cache");
static_assert(NJ % 4 == 0 && NM % 4 == 0, "4-row packing needs n % 4 == 0");

typedef float v2f __attribute__((ext_vector_type(2)));

struct Params {
    const float *jobs, *machines;
    const int *mask;
    const float *jW1, *jb1, *jW2, *jb2;
    const float *mW1, *mb1, *mW2, *mb2;
    const float *aj_Wq, *aj_bq, *aj_Wr, *aj_V;
    const float *am_Wq, *am_bq, *am_Wr, *am_V;
    const float *ja_Wq, *ja_bq, *ja_Wr, *ja_V;
    const float *ma_Wq, *ma_bq, *ma_Wr, *ma_V;
    const float *g1W, *g1b, *g2W, *g2b, *last_j;
    float *S;        // smalls + partials (in ws)
    float *Ej, *Em;  // embedding cache tiles (in ws; valid only if CACHE)
    float *out;
};

// ---------------------------------------------------------------------------
// device helpers
// ---------------------------------------------------------------------------

// tanh(x) = 1 - 2*rcp(exp2(x*2*log2e)+1). 5 instrs. abs err ~2e-7 vs np.tanh.
__device__ __forceinline__ float fast_tanh(float x) {
    float e = __builtin_amdgcn_exp2f(x * 2.8853900817779268f);  // 2/ln2
    float r = __builtin_amdgcn_rcpf(e + 1.0f);
    return fmaf(-2.0f, r, 1.0f);
}

__device__ __forceinline__ v2f vbc(float a) { v2f r; r.x = a; r.y = a; return r; }

// packed fma: one v_pk_fma_f32 issue slot for two fp32 FMAs (bit-identical)
__device__ __forceinline__ v2f vfma(float w, v2f b, v2f c) {
    return __builtin_elementwise_fma(vbc(w), b, c);
}
__device__ __forceinline__ v2f vfma2(v2f a, v2f b, v2f c) {
    return __builtin_elementwise_fma(a, b, c);
}
__device__ __forceinline__ v2f vtanh(v2f a) {
    v2f r; r.x = fast_tanh(a.x); r.y = fast_tanh(a.y); return r;
}

__device__ __forceinline__ void load16(const float* __restrict__ X, size_t r, float (&x)[16]) {
    const float4* p4 = reinterpret_cast<const float4*>(X) + r * 4;
    float4 a = p4[0], b = p4[1], c = p4[2], d = p4[3];
    x[0]=a.x; x[1]=a.y; x[2]=a.z; x[3]=a.w;
    x[4]=b.x; x[5]=b.y; x[6]=b.z; x[7]=b.w;
    x[8]=c.x; x[9]=c.y; x[10]=c.z; x[11]=c.w;
    x[12]=d.x; x[13]=d.y; x[14]=d.z; x[15]=d.w;
}

// load rows rA, rB and pack feature-wise into v2f lanes (.x=rowA, .y=rowB)
__device__ __forceinline__ void load16_v2(const float* __restrict__ X, size_t rA, size_t rB,
                                          v2f (&x)[16]) {
    float a[16], b[16];
    load16(X, rA, a);
    load16(X, rB, b);
#pragma unroll
    for (int k = 0; k < 16; ++k) { x[k].x = a[k]; x[k].y = b[k]; }
}

// E-cache tile for 4 rows/thread: [8][2 pairs][256 threads * float4].
// thread t owns rows (4t..4t+3): pair g slot = kp*512 + g*256 + t
// (16B/lane, lane-contiguous within each (kp,g) slab).
__device__ __forceinline__ void ecache_store4(float* __restrict__ Eb, int t,
                                              const v2f (&e0)[16], const v2f (&e1)[16]) {
    float4* p4 = reinterpret_cast<float4*>(Eb);
#pragma unroll
    for (int kp = 0; kp < 8; ++kp) {
        p4[kp * 512 + t]       = make_float4(e0[2*kp].x, e0[2*kp].y, e0[2*kp+1].x, e0[2*kp+1].y);
        p4[kp * 512 + 256 + t] = make_float4(e1[2*kp].x, e1[2*kp].y, e1[2*kp+1].x, e1[2*kp+1].y);
    }
}
__device__ __forceinline__ void ecache_load4(const float* __restrict__ Eb, int t,
                                             v2f (&e0)[16], v2f (&e1)[16]) {
    const float4* p4 = reinterpret_cast<const float4*>(Eb);
#pragma unroll
    for (int kp = 0; kp < 8; ++kp) {
        float4 q0 = p4[kp * 512 + t];
        float4 q1 = p4[kp * 512 + 256 + t];
        e0[2*kp].x = q0.x;   e0[2*kp].y = q0.y;
        e0[2*kp+1].x = q0.z; e0[2*kp+1].y = q0.w;
        e1[2*kp].x = q1.x;   e1[2*kp].y = q1.y;
        e1[2*kp+1].x = q1.z; e1[2*kp+1].y = q1.w;
    }
}

// e = tanh(W2 @ tanh(W1 @ x + b1) + b2) for a packed row-pair
__device__ __forceinline__ void emb16_v2(const v2f (&x)[16],
                                         const float* __restrict__ W1, const float* __restrict__ b1,
                                         const float* __restrict__ W2, const float* __restrict__ b2,
                                         v2f (&e)[16]) {
    v2f h[16];
#pragma unroll
    for (int i = 0; i < 16; ++i) {
        v2f a = vbc(b1[i]);
#pragma unroll
        for (int k = 0; k < 16; ++k) a = vfma(W1[i * 16 + k], x[k], a);
        h[i] = vtanh(a);
    }
#pragma unroll
    for (int i = 0; i < 16; ++i) {
        v2f a = vbc(b2[i]);
#pragma unroll
        for (int k = 0; k < 16; ++k) a = vfma(W2[i * 16 + k], h[k], a);
        e[i] = vtanh(a);
    }
}

// logit = tanh(qk + Wr @ e) . V for a packed row-pair
__device__ __forceinline__ v2f att_logit_v2(const v2f (&e)[16], const float (&qk)[16],
                                            const float* __restrict__ Wr,
                                            const float* __restrict__ V) {
    v2f acc = vbc(0.0f);
#pragma unroll
    for (int i = 0; i < 16; ++i) {
        v2f r = vbc(qk[i]);
#pragma unroll
        for (int k = 0; k < 16; ++k) r = vfma(Wr[i * 16 + k], e[k], r);
        acc = vfma2(vbc(V[i]), vtanh(r), acc);
    }
    return acc;
}

__device__ __forceinline__ float wave_reduce_sum(float v) {
#pragma unroll
    for (int off = 32; off > 0; off >>= 1) v += __shfl_xor(v, off, 64);
    return v;
}

__device__ __forceinline__ void wave_reduce_argmax(float &v, int &idx) {
#pragma unroll
    for (int off = 32; off > 0; off >>= 1) {
        float ov = __shfl_xor(v, off, 64);
        int oi = __shfl_xor(idx, off, 64);
        if (ov > v || (ov == v && oi < idx)) { v = ov; idx = oi; }
    }
}

__device__ __forceinline__ float block_sum(float v) {
    __shared__ float sm[4];
    v = wave_reduce_sum(v);
    __syncthreads();
    if ((threadIdx.x & 63) == 0) sm[threadIdx.x >> 6] = v;
    __syncthreads();
    return sm[0] + sm[1] + sm[2] + sm[3];
}

__device__ __forceinline__ void block_argmax(float &v, int &i) {
    __shared__ float sv[4];
    __shared__ int si[4];
    wave_reduce_argmax(v, i);
    __syncthreads();
    if ((threadIdx.x & 63) == 0) { sv[threadIdx.x >> 6] = v; si[threadIdx.x >> 6] = i; }
    __syncthreads();
    float bv = sv[0]; int bi = si[0];
#pragma unroll
    for (int k = 1; k < 4; ++k)
        if (sv[k] > bv || (sv[k] == bv && si[k] < bi)) { bv = sv[k]; bi = si[k]; }
    v = bv; i = bi;
}

// Block-reduce (l, s[16]) -> dst[17] via reduce-scatter butterflies.
// OUTPUT LAYOUT (contract with all readers): dst[0] = l, dst[1+j] = s[j].
// 23 DS ops/wave vs 102 naive. Verified in R7/R9 (absmax 0 across all sites).
__device__ __forceinline__ void block_sum17(float l, const float (&s)[16], float* dst) {
    const int lane = threadIdx.x & 63;
    float c[8];
#pragma unroll
    for (int j = 0; j < 8; ++j) {          // xor 1: 16 -> 8
        const bool hi = lane & 1;
        float t = __shfl_xor(hi ? s[j] : s[j + 8], 1, 64);
        c[j] = (hi ? s[j + 8] : s[j]) + t;
    }
    float d[4];
#pragma unroll
    for (int j = 0; j < 4; ++j) {          // xor 2: 8 -> 4
        const bool hi = lane & 2;
        float t = __shfl_xor(hi ? c[j] : c[j + 4], 2, 64);
        d[j] = (hi ? c[j + 4] : c[j]) + t;
    }
    float e2[2];
#pragma unroll
    for (int j = 0; j < 2; ++j) {          // xor 4: 4 -> 2
        const bool hi = lane & 4;
        float t = __shfl_xor(hi ? d[j] : d[j + 2], 4, 64);
        e2[j] = (hi ? d[j + 2] : d[j]) + t;
    }
    float f;
    {                                       // xor 8: 2 -> 1
        const bool hi = lane & 8;
        float t = __shfl_xor(hi ? e2[0] : e2[1], 8, 64);
        f = (hi ? e2[1] : e2[0]) + t;
    }
    f += __shfl_xor(f, 16, 64);             // merge 16-lane groups
    f += __shfl_xor(f, 32, 64);
#pragma unroll
    for (int off = 32; off > 0; off >>= 1) l += __shfl_xor(l, off, 64);

    const int idx = ((lane & 1) << 3) | ((lane & 2) << 1) | ((lane & 4) >> 1) | ((lane & 8) >> 3);
    __shared__ float red[4][17];
    const int w = threadIdx.x >> 6;
    __syncthreads();                        // guard reuse across successive calls
    if (lane < 16) red[w][1 + idx] = f;     // s[idx] -> dst[1+idx]
    if (lane == 0) red[w][0] = l;           // l      -> dst[0]
    __syncthreads();
    if (threadIdx.x < 17)
        dst[threadIdx.x] = red[0][threadIdx.x] + red[1][threadIdx.x] + red[2][threadIdx.x] + red[3][threadIdx.x];
}

// weighted sum of 4 rows: s[i] = w01 . e0[i] + w23 . e1[i]  (3 ops/feature)
__device__ __forceinline__ void wsum4(const v2f (&e0)[16], const v2f (&e1)[16],
                                      v2f w01, v2f w23, float (&s)[16]) {
#pragma unroll
    for (int i = 0; i < 16; ++i) {
        v2f t = vfma2(w23, e1[i], w01 * e0[i]);
        s[i] = t.x + t.y;
    }
}

// ---------------------------------------------------------------------------
// K1: embeddings (cached to ws if CACHE) + glimpse-1 partial sums.
// blocks [0,GB_J) -> jobs, [GB_J,GB_TOT) -> machines. Rows (4t..4t+3).
// ---------------------------------------------------------------------------
template <bool CACHE>
__global__ __launch_bounds__(BLK) void k_emb_g1(Params p) {
    const bool isJob = blockIdx.x < GB_J;
    const float* X  = isJob ? p.jobs : p.machines;
    const float* W1 = isJob ? p.jW1 : p.mW1;
    const float* b1 = isJob ? p.jb1 : p.mb1;
    const float* W2 = isJob ? p.jW2 : p.mW2;
    const float* b2 = isJob ? p.jb2 : p.mb2;
    const float* Wr = isJob ? p.aj_Wr : p.am_Wr;
    const float* V  = isJob ? p.aj_V  : p.am_V;
    float* E = isJob ? p.Ej : p.Em;
    const int n  = isJob ? NJ : NM;
    const int b0 = isJob ? (int)blockIdx.x : (int)blockIdx.x - GB_J;

    const int r0 = b0 * ROWS_PER_BLK + 4 * (int)threadIdx.x;
    const bool v = r0 < n;                 // n%4==0 => all 4 rows valid together
    const size_t a0 = v ? (size_t)r0 : 0;
    const size_t d  = v ? 1 : 0;

    // issue all 16 global loads first (latency overlaps the qk prologue)
    v2f x0[16], x1[16];
    load16_v2(X, a0, a0 + d, x0);
    load16_v2(X, a0 + 2 * d, a0 + 3 * d, x1);

    __shared__ float qks[16];
    if (threadIdx.x < 16) {
        const float* Wq = isJob ? p.aj_Wq : p.am_Wq;
        const float* bq = isJob ? p.aj_bq : p.am_bq;
        const int i = threadIdx.x;
        float a = bq[i];
#pragma unroll
        for (int k = 0; k < 16; ++k) a = fmaf(Wq[i * 16 + k], p.last_j[k], a);
        qks[i] = a;
    }
    __syncthreads();
    float qk[16];
#pragma unroll
    for (int i = 0; i < 16; ++i) qk[i] = qks[i];

    v2f e0[16], e1[16];
    emb16_v2(x0, W1, b1, W2, b2, e0);
    emb16_v2(x1, W1, b1, W2, b2, e1);
    if (CACHE) ecache_store4(E + (size_t)b0 * EBLK, (int)threadIdx.x, e0, e1);
    v2f lg0 = att_logit_v2(e0, qk, Wr, V);
    v2f lg1 = att_logit_v2(e1, qk, Wr, V);
    // |logit| <= sum|V| ~ 0.6 -> exp never overflows; no max-shift needed.
    v2f w01, w23;
    w01.x = v ? __expf(lg0.x) : 0.0f;
    w01.y = v ? __expf(lg0.y) : 0.0f;
    w23.x = v ? __expf(lg1.x) : 0.0f;
    w23.y = v ? __expf(lg1.y) : 0.0f;
    float l = (w01.x + w01.y) + (w23.x + w23.y);
    float s[16];
    wsum4(e0, e1, w01, w23, s);

    block_sum17(l, s, p.S + (isJob ? P1J : P1M) + (size_t)b0 * 17);
}

// ---------------------------------------------------------------------------
// Combine partials -> g (g1 or g2) -> next-stage qk vector. Single block.
// ---------------------------------------------------------------------------
__global__ __launch_bounds__(BLK) void k_combine_g(Params p, int phase) {
    const float* PJ = p.S + P1J;
    const float* PM = p.S + P1M;
    float lJ = 0.0f, lM = 0.0f, sJ[16], sM[16];
#pragma unroll
    for (int c = 0; c < 16; ++c) { sJ[c] = 0.0f; sM[c] = 0.0f; }
    for (int i = threadIdx.x; i < GB_J; i += BLK) {
        lJ += PJ[i * 17];
#pragma unroll
        for (int c = 0; c < 16; ++c) sJ[c] += PJ[i * 17 + 1 + c];
    }
    for (int i = threadIdx.x; i < GB_M; i += BLK) {
        lM += PM[i * 17];
#pragma unroll
        for (int c = 0; c < 16; ++c) sM[c] += PM[i * 17 + 1 + c];
    }
    __shared__ float totJ[17], totM[17];
    block_sum17(lJ, sJ, totJ);
    block_sum17(lM, sM, totM);
    __syncthreads();

    __shared__ float cb[48], gbuf[16];
    if (threadIdx.x < 16) {
        int i = threadIdx.x;
        cb[i]      = phase ? p.S[S_EJS + i] : p.last_j[i];
        cb[16 + i] = totJ[1 + i] / totJ[0];   // softmax-weighted sum / partition
        cb[32 + i] = totM[1 + i] / totM[0];
    }
    __syncthreads();
    const float* gW  = phase ? p.g2W : p.g1W;
    const float* gbv = phase ? p.g2b : p.g1b;
    if (threadIdx.x < 16) {
        int i = threadIdx.x;
        float a = gbv[i];
#pragma unroll
        for (int k = 0; k < 48; ++k) a = fmaf(gW[i * 48 + k], cb[k], a);
        gbuf[i] = fast_tanh(a);
    }
    __syncthreads();
    const float* Wq = phase ? p.ma_Wq : p.ja_Wq;
    const float* bq = phase ? p.ma_bq : p.ja_bq;
    const int off = phase ? S_QKMA : S_QKJA;
    if (threadIdx.x < 16) {
        int i = threadIdx.x;
        float a = bq[i];
#pragma unroll
        for (int k = 0; k < 16; ++k) a = fmaf(Wq[i * 16 + k], gbuf[k], a);
        p.S[off + i] = a;
    }
}

// ---------------------------------------------------------------------------
// K3: job pointer logits -> masked argmax + sum-exp partials. Rows (4t..4t+3).
// ---------------------------------------------------------------------------
template <bool CACHE>
__global__ __launch_bounds__(BLK) void k_jlogits(Params p) {
    const int r0 = blockIdx.x * ROWS_PER_BLK + 4 * (int)threadIdx.x;
    const bool v = r0 < NJ;
    const size_t a0 = v ? (size_t)r0 : 0;
    const size_t d  = v ? 1 : 0;

    v2f e0[16], e1[16];
    if (CACHE) {
        ecache_load4(p.Ej + (size_t)blockIdx.x * EBLK, (int)threadIdx.x, e0, e1);
    } else {
        v2f x0[16], x1[16];
        load16_v2(p.jobs, a0, a0 + d, x0);
        load16_v2(p.jobs, a0 + 2 * d, a0 + 3 * d, x1);
        emb16_v2(x0, p.jW1, p.jb1, p.jW2, p.jb2, e0);
        emb16_v2(x1, p.jW1, p.jb1, p.jW2, p.jb2, e1);
    }
    float qk[16];
#pragma unroll
    for (int i = 0; i < 16; ++i) qk[i] = p.S[S_QKJA + i];

    v2f lg0 = att_logit_v2(e0, qk, p.ja_Wr, p.ja_V);
    v2f lg1 = att_logit_v2(e1, qk, p.ja_Wr, p.ja_V);

    int4 mq = make_int4(0, 0, 0, 0);
    if (v) mq = *reinterpret_cast<const int4*>(p.mask + r0);   // r0 mult of 4 -> 16B aligned
    const bool m0 = v && (mq.x != 0);
    const bool m1 = v && (mq.y != 0);
    const bool m2 = v && (mq.z != 0);
    const bool m3 = v && (mq.w != 0);
    float l = (m0 ? __expf(lg0.x) : 0.0f) + (m1 ? __expf(lg0.y) : 0.0f)
            + (m2 ? __expf(lg1.x) : 0.0f) + (m3 ? __expf(lg1.y) : 0.0f);
    float am0 = m0 ? lg0.x : NEGV - 1.0f;  // invalid rows below masked NEG
    float am1 = m1 ? lg0.y : NEGV - 1.0f;
    float am2 = m2 ? lg1.x : NEGV - 1.0f;
    float am3 = m3 ? lg1.y : NEGV - 1.0f;
    float best = am0; int bi = r0;
    if (am1 > best) { best = am1; bi = r0 + 1; }
    if (am2 > best) { best = am2; bi = r0 + 2; }
    if (am3 > best) { best = am3; bi = r0 + 3; }

    l = wave_reduce_sum(l);
    wave_reduce_argmax(best, bi);
    __shared__ float rl[4], rv[4];
    __shared__ int ri[4];
    int w = threadIdx.x >> 6, ln = threadIdx.x & 63;
    if (ln == 0) { rl[w] = l; rv[w] = best; ri[w] = bi; }
    __syncthreads();
    if (threadIdx.x == 0) {
        float L = rl[0] + rl[1] + rl[2] + rl[3];
        float vv = rv[0]; int i = ri[0];
#pragma unroll
        for (int k = 1; k < 4; ++k)
            if (rv[k] > vv || (rv[k] == vv && ri[k] < i)) { vv = rv[k]; i = ri[k]; }
        p.S[P2V + blockIdx.x] = vv;
        p.S[P2I + blockIdx.x] = (float)i;   // exact: i < 2^24
        p.S[P2L + blockIdx.x] = L;
    }
}

// ---------------------------------------------------------------------------
// C2: global argmax over job logits; logp_j; e_js = emb(jobs[sel_j]); qk2j/qk2m
// ---------------------------------------------------------------------------
__global__ __launch_bounds__(BLK) void k_combine2(Params p) {
    float v = -3.4e38f; int vi = 0x7fffffff; float l = 0.0f;
    for (int i = threadIdx.x; i < GB_J; i += BLK) {
        float pv = p.S[P2V + i];
        int pi = (int)p.S[P2I + i];
        if (pv > v || (pv == v && pi < vi)) { v = pv; vi = pi; }
        l += p.S[P2L + i];
    }
    l = block_sum(l);
    block_argmax(v, vi);
    const int sel = vi;

    __shared__ float xb[16], hb[16], eb[16];
    if (threadIdx.x < 16) xb[threadIdx.x] = p.jobs[(size_t)sel * 16 + threadIdx.x];
    __syncthreads();
    if (threadIdx.x < 16) {
        int i = threadIdx.x;
        float a = p.jb1[i];
#pragma unroll
        for (int k = 0; k < 16; ++k) a = fmaf(p.jW1[i * 16 + k], xb[k], a);
        hb[i] = fast_tanh(a);
    }
    __syncthreads();
    if (threadIdx.x < 16) {
        int i = threadIdx.x;
        float a = p.jb2[i];
#pragma unroll
        for (int k = 0; k < 16; ++k) a = fmaf(p.jW2[i * 16 + k], hb[k], a);
        float e = fast_tanh(a);
        eb[i] = e;
        p.S[S_EJS + i] = e;
    }
    __syncthreads();
    if (threadIdx.x < 16) {
        int i = threadIdx.x;
        float a1 = p.aj_bq[i], a2 = p.am_bq[i];
#pragma unroll
        for (int k = 0; k < 16; ++k) {
            a1 = fmaf(p.aj_Wq[i * 16 + k], eb[k], a1);
            a2 = fmaf(p.am_Wq[i * 16 + k], eb[k], a2);
        }
        p.S[S_QK2J + i] = a1;
        p.S[S_QK2M + i] = a2;
    }
    if (threadIdx.x == 0) {
        p.S[S_LOGPJ] = v - logf(l);     // log_softmax at the argmax
        p.S[S_SELJ] = (float)sel;
    }
}

// ---------------------------------------------------------------------------
// K4: glimpse-2 over jobs (aj_*) and machines (am_*), query e_js. Rows (4t..4t+3).
// Writes partials into the (already consumed) P1 buffers.
// ---------------------------------------------------------------------------
template <bool CACHE>
__global__ __launch_bounds__(BLK) void k_glimpse2(Params p) {
    const bool isJob = blockIdx.x < GB_J;
    const float* Wr = isJob ? p.aj_Wr : p.am_Wr;
    const float* V  = isJob ? p.aj_V  : p.am_V;
    const float* E  = isJob ? p.Ej : p.Em;
    const float* X  = isJob ? p.jobs : p.machines;
    const float* W1 = isJob ? p.jW1 : p.mW1;
    const float* b1 = isJob ? p.jb1 : p.mb1;
    const float* W2 = isJob ? p.jW2 : p.mW2;
    const float* b2 = isJob ? p.jb2 : p.mb2;
    const int n  = isJob ? NJ : NM;
    const int b0 = isJob ? (int)blockIdx.x : (int)blockIdx.x - GB_J;
    const int qoff = isJob ? S_QK2J : S_QK2M;

    const int r0 = b0 * ROWS_PER_BLK + 4 * (int)threadIdx.x;
    const bool v = r0 < n;
    const size_t a0 = v ? (size_t)r0 : 0;
    const size_t d  = v ? 1 : 0;

    v2f e0[16], e1[16];
    if (CACHE) {
        ecache_load4(E + (size_t)b0 * EBLK, (int)threadIdx.x, e0, e1);
    } else {
        v2f x0[16], x1[16];
        load16_v2(X, a0, a0 + d, x0);
        load16_v2(X, a0 + 2 * d, a0 + 3 * d, x1);
        emb16_v2(x0, W1, b1, W2, b2, e0);
        emb16_v2(x1, W1, b1, W2, b2, e1);
    }
    float qk[16];
#pragma unroll
    for (int i = 0; i < 16; ++i) qk[i] = p.S[qoff + i];

    v2f lg0 = att_logit_v2(e0, qk, Wr, V);
    v2f lg1 = att_logit_v2(e1, qk, Wr, V);
    v2f w01, w23;
    w01.x = v ? __expf(lg0.x) : 0.0f;
    w01.y = v ? __expf(lg0.y) : 0.0f;
    w23.x = v ? __expf(lg1.x) : 0.0f;
    w23.y = v ? __expf(lg1.y) : 0.0f;
    float l = (w01.x + w01.y) + (w23.x + w23.y);
    float s[16];
    wsum4(e0, e1, w01, w23, s);

    block_sum17(l, s, p.S + (isJob ? P1J : P1M) + (size_t)b0 * 17);
}

// ---------------------------------------------------------------------------
// K5: machine logits -> argmax + sum-exp partials. Rows (4t..4t+3).
// Writes into the (already consumed) P2 buffers.
// ---------------------------------------------------------------------------
template <bool CACHE>
__global__ __launch_bounds__(BLK) void k_mlogits(Params p) {
    const int r0 = blockIdx.x * ROWS_PER_BLK + 4 * (int)threadIdx.x;
    const bool v = r0 < NM;
    const size_t a0 = v ? (size_t)r0 : 0;
    const size_t d  = v ? 1 : 0;

    v2f e0[16], e1[16];
    if (CACHE) {
        ecache_load4(p.Em + (size_t)blockIdx.x * EBLK, (int)threadIdx.x, e0, e1);
    } else {
        v2f x0[16], x1[16];
        load16_v2(p.machines, a0, a0 + d, x0);
        load16_v2(p.machines, a0 + 2 * d, a0 + 3 * d, x1);
        emb16_v2(x0, p.mW1, p.mb1, p.mW2, p.mb2, e0);
        emb16_v2(x1, p.mW1, p.mb1, p.mW2, p.mb2, e1);
    }
    float qk[16];
#pragma unroll
    for (int i = 0; i < 16; ++i) qk[i] = p.S[S_QKMA + i];

    v2f lg0 = att_logit_v2(e0, qk, p.ma_Wr, p.ma_V);
    v2f lg1 = att_logit_v2(e1, qk, p.ma_Wr, p.ma_V);
    float l = (v ? __expf(lg0.x) : 0.0f) + (v ? __expf(lg0.y) : 0.0f)
            + (v ? __expf(lg1.x) : 0.0f) + (v ? __expf(lg1.y) : 0.0f);
    float am0 = v ? lg0.x : -3.4e38f;
    float am1 = v ? lg0.y : -3.4e38f;
    float am2 = v ? lg1.x : -3.4e38f;
    float am3 = v ? lg1.y : -3.4e38f;
    float best = am0; int bi = r0;
    if (am1 > best) { best = am1; bi = r0 + 1; }
    if (am2 > best) { best = am2; bi = r0 + 2; }
    if (am3 > best) { best = am3; bi = r0 + 3; }

    l = wave_reduce_sum(l);
    wave_reduce_argmax(best, bi);
    __shared__ float rl[4], rv[4];
    __shared__ int ri[4];
    int w = threadIdx.x >> 6, ln = threadIdx.x & 63;
    if (ln == 0) { rl[w] = l; rv[w] = best; ri[w] = bi; }
    __syncthreads();
    if (threadIdx.x == 0) {
        float L = rl[0] + rl[1] + rl[2] + rl[3];
        float vv = rv[0]; int i = ri[0];
#pragma unroll
        for (int k = 1; k < 4; ++k)
            if (rv[k] > vv || (rv[k] == vv && ri[k] < i)) { vv = rv[k]; i = ri[k]; }
        p.S[P2V + blockIdx.x] = vv;
        p.S[P2I + blockIdx.x] = (float)i;
        p.S[P2L + blockIdx.x] = L;
    }
}

// ---------------------------------------------------------------------------
// C4: final combine -> outputs [sel_j, sel_m, logpas] as float32
// ---------------------------------------------------------------------------
__global__ __launch_bounds__(BLK) void k_combine4(Params p) {
    float v = -3.4e38f; int vi = 0x7fffffff; float l = 0.0f;
    for (int i = threadIdx.x; i < GB_M; i += BLK) {
        float pv = p.S[P2V + i];
        int pi = (int)p.S[P2I + i];
        if (pv > v || (pv == v && pi < vi)) { v = pv; vi = pi; }
        l += p.S[P2L + i];
    }
    l = block_sum(l);
    block_argmax(v, vi);
    if (threadIdx.x == 0) {
        p.out[0] = p.S[S_SELJ];
        p.out[1] = (float)vi;
        p.out[2] = p.S[S_LOGPJ] + (v - logf(l));
    }
}

// ---------------------------------------------------------------------------
extern "C" void kernel_launch(void* const* d_in, const int* in_sizes, int n_in,
                              void* d_out, int out_size, void* d_ws, size_t ws_size,
                              hipStream_t stream) {
    Params p;
    p.jobs     = (const float*)d_in[0];
    p.machines = (const float*)d_in[1];
    p.mask     = (const int*)d_in[2];
    p.jW1 = (const float*)d_in[3];  p.jb1 = (const float*)d_in[4];
    p.jW2 = (const float*)d_in[5];  p.jb2 = (const float*)d_in[6];
    p.mW1 = (const float*)d_in[7];  p.mb1 = (const float*)d_in[8];
    p.mW2 = (const float*)d_in[9];  p.mb2 = (const float*)d_in[10];
    p.aj_Wq = (const float*)d_in[11]; p.aj_bq = (const float*)d_in[12];
    p.aj_Wr = (const float*)d_in[13]; p.aj_V  = (const float*)d_in[14];
    p.am_Wq = (const float*)d_in[15]; p.am_bq = (const float*)d_in[16];
    p.am_Wr = (const float*)d_in[17]; p.am_V  = (const float*)d_in[18];
    p.ja_Wq = (const float*)d_in[19]; p.ja_bq = (const float*)d_in[20];
    p.ja_Wr = (const float*)d_in[21]; p.ja_V  = (const float*)d_in[22];
    p.ma_Wq = (const float*)d_in[23]; p.ma_bq = (const float*)d_in[24];
    p.ma_Wr = (const float*)d_in[25]; p.ma_V  = (const float*)d_in[26];
    p.g1W = (const float*)d_in[27]; p.g1b = (const float*)d_in[28];
    p.g2W = (const float*)d_in[29]; p.g2b = (const float*)d_in[30];
    p.last_j = (const float*)d_in[31];
    p.S = (float*)d_ws;
    p.Ej = (float*)d_ws + E_OFF;
    p.Em = p.Ej + (size_t)GB_J * EBLK;
    p.out = (float*)d_out;

    const size_t needed = (E_OFF + (size_t)GB_TOT * EBLK) * sizeof(float);
    const bool cache = ws_size >= needed;

    if (cache) {
        k_emb_g1<true><<<GB_TOT, BLK, 0, stream>>>(p);
        k_combine_g<<<1, BLK, 0, stream>>>(p, 0);
        k_jlogits<true><<<GB_J, BLK, 0, stream>>>(p);
        k_combine2<<<1, BLK, 0, stream>>>(p);
        k_glimpse2<true><<<GB_TOT, BLK, 0, stream>>>(p);
        k_combine_g<<<1, BLK, 0, stream>>>(p, 1);
        k_mlogits<true><<<GB_M, BLK, 0, stream>>>(p);
        k_combine4<<<1, BLK, 0, stream>>>(p);
    } else {
        k_emb_g1<false><<<GB_TOT, BLK, 0, stream>>>(p);
        k_combine_g<<<1, BLK, 0, stream>>>(p, 0);
        k_jlogits<false><<<GB_J, BLK, 0, stream>>>(p);
        k_combine2<<<1, BLK, 0, stream>>>(p);
        k_glimpse2<false><<<GB_TOT, BLK, 0, stream>>>(p);
        k_combine_g<<<1, BLK, 0, stream>>>(p, 1);
        k_mlogits<false><<<GB_M, BLK, 0, stream>>>(p);
        k_combine4<<<1, BLK, 0, stream>>>(p);
    }
}